// Round 1
// baseline (448.574 us; speedup 1.0000x reference)
//
#include <hip/hip_runtime.h>

#define C_INn 8
#define C_OUTn 8
#define NBn 16
#define Sn 64
#define OSn 66            // S + K - 1
#define YT 11             // y rows per block
#define NYT 6             // 66 / 11
#define TPB 256
#define PTS (YT * OSn)    // 726 points per block
#define SCALEf 2.0f
#define EPSf 1e-5f

// ws layout (floats): [0,128) accum[n][co] ; [128,136) A[co]; [136,144) B[co];
//                     [144,144+1728) wq[ci][tap][co]  (pre-flipped weights)

__global__ void prep_kernel(const float* __restrict__ w,
                            const float* __restrict__ bias,
                            const float* __restrict__ mean,
                            const float* __restrict__ var,
                            const float* __restrict__ gamma,
                            const float* __restrict__ beta,
                            float* __restrict__ ws) {
    int tid = blockIdx.x * blockDim.x + threadIdx.x;
    if (tid < 128) ws[tid] = 0.0f;                   // zero the accumulator
    if (tid < C_OUTn) {
        float inv = rsqrtf(var[tid] + EPSf);
        float A = SCALEf * inv * gamma[tid];
        float B = (bias[tid] * SCALEf - mean[tid]) * inv * gamma[tid] + beta[tid];
        ws[128 + tid] = A;
        ws[136 + tid] = B;
    }
    // wq[ci][ez][ey][ex][co] = w[co][ci][2-ez][2-ey][2-ex]
    int total = C_INn * 27 * C_OUTn;                 // 1728
    for (int i = tid; i < total; i += gridDim.x * blockDim.x) {
        int co = i & 7;
        int t  = (i >> 3) % 27;
        int ci = i / (27 * 8);
        int ez = t / 9, ey = (t / 3) % 3, ex = t % 3;
        int sz = 2 - ez, sy = 2 - ey, sx = 2 - ex;
        ws[144 + i] = w[(co * C_INn + ci) * 27 + sz * 9 + sy * 3 + sx];
    }
}

__global__ __launch_bounds__(TPB) void convpool_kernel(
        const float* __restrict__ x, float* __restrict__ ws) {
    __shared__ float xs[3 * 13 * 68];    // padded slab: z(3) x y(13) x x(68)
    __shared__ float red[4][C_OUTn];

    const int tid = threadIdx.x;
    const int yt = blockIdx.x;           // 0..5
    const int zo = blockIdx.y;           // 0..65
    const int n  = blockIdx.z;           // 0..15
    const int ybase = yt * YT;

    // per-channel affine
    float A[C_OUTn], Bv[C_OUTn];
#pragma unroll
    for (int c = 0; c < C_OUTn; c++) { A[c] = ws[128 + c]; Bv[c] = ws[136 + c]; }

    // this thread's 3 output points (local ids), masked if >= PTS
    int bofs[3]; bool valid[3];
#pragma unroll
    for (int p = 0; p < 3; p++) {
        int q = tid + p * TPB;
        valid[p] = (q < PTS);
        if (!valid[p]) q = 0;
        int yl = q / OSn;                // yo - ybase, 0..10
        int xo = q % OSn;                // 0..65
        bofs[p] = yl * 68 + xo;
    }

    float acc[3][C_OUTn];
#pragma unroll
    for (int p = 0; p < 3; p++)
#pragma unroll
        for (int c = 0; c < C_OUTn; c++) acc[p][c] = 0.0f;

    const float* xn = x + (size_t)n * C_INn * (Sn * Sn * Sn);
    const float* wq = ws + 144;

    for (int ci = 0; ci < C_INn; ci++) {
        __syncthreads();   // protect xs against readers of previous iter
        const float* xc = xn + ci * (Sn * Sn * Sn);
        for (int idx = tid; idx < 3 * 13 * 68; idx += TPB) {
            int c  = idx % 68;
            int rr = idx / 68;
            int r  = rr % 13;
            int dz = rr / 13;
            int zi = zo - 2 + dz;
            int yi = ybase - 2 + r;
            int xi = c - 2;
            float v = 0.0f;
            if ((unsigned)zi < Sn && (unsigned)yi < Sn && (unsigned)xi < Sn)
                v = xc[((zi * Sn) + yi) * Sn + xi];
            xs[idx] = v;
        }
        __syncthreads();

        const float* wci = wq + ci * 27 * C_OUTn;
#pragma unroll
        for (int ez = 0; ez < 3; ez++)
#pragma unroll
        for (int ey = 0; ey < 3; ey++)
#pragma unroll
        for (int ex = 0; ex < 3; ex++) {
            const int t = (ez * 3 + ey) * 3 + ex;
            const float* wp = wci + t * C_OUTn;     // uniform address -> s_load
            float xv[3];
#pragma unroll
            for (int p = 0; p < 3; p++)
                xv[p] = xs[(ez * 13 + ey) * 68 + bofs[p] + ex];
#pragma unroll
            for (int p = 0; p < 3; p++)
#pragma unroll
                for (int c = 0; c < C_OUTn; c++)
                    acc[p][c] = fmaf(xv[p], wp[c], acc[p][c]);
        }
    }

    // affine + ReLU + per-thread sum
    float csum[C_OUTn];
#pragma unroll
    for (int c = 0; c < C_OUTn; c++) {
        float s = 0.0f;
#pragma unroll
        for (int p = 0; p < 3; p++) {
            float v = fmaf(A[c], acc[p][c], Bv[c]);
            v = fmaxf(v, 0.0f);
            s += valid[p] ? v : 0.0f;
        }
        csum[c] = s;
    }

    // wave reduction (64 lanes), then cross-wave via LDS
#pragma unroll
    for (int off = 32; off > 0; off >>= 1)
#pragma unroll
        for (int c = 0; c < C_OUTn; c++)
            csum[c] += __shfl_down(csum[c], off, 64);

    const int wave = tid >> 6, lane = tid & 63;
    if (lane == 0)
#pragma unroll
        for (int c = 0; c < C_OUTn; c++) red[wave][c] = csum[c];
    __syncthreads();
    if (tid < C_OUTn) {
        float s = red[0][tid] + red[1][tid] + red[2][tid] + red[3][tid];
        atomicAdd(&ws[n * C_OUTn + tid], s);
    }
}

__global__ void finalize_kernel(const float* __restrict__ ws, float* __restrict__ out) {
    int t = threadIdx.x;
    if (t < 128) out[t] = ws[t] * (1.0f / (66.0f * 66.0f * 66.0f));
}

extern "C" void kernel_launch(void* const* d_in, const int* in_sizes, int n_in,
                              void* d_out, int out_size, void* d_ws, size_t ws_size,
                              hipStream_t stream) {
    const float* x      = (const float*)d_in[0];
    const float* weight = (const float*)d_in[1];
    const float* bias   = (const float*)d_in[2];
    const float* rmean  = (const float*)d_in[3];
    const float* rvar   = (const float*)d_in[4];
    const float* gamma  = (const float*)d_in[5];
    const float* beta   = (const float*)d_in[6];
    float* ws  = (float*)d_ws;
    float* out = (float*)d_out;

    prep_kernel<<<7, TPB, 0, stream>>>(weight, bias, rmean, rvar, gamma, beta, ws);

    dim3 grid(NYT, OSn, NBn);   // 6 x 66 x 16 = 6336 blocks
    convpool_kernel<<<grid, TPB, 0, stream>>>(x, ws);

    finalize_kernel<<<1, 128, 0, stream>>>(ws, out);
}

// Round 2
// 267.746 us; speedup vs baseline: 1.6754x; 1.6754x over previous
//
#include <hip/hip_runtime.h>

typedef __attribute__((ext_vector_type(8))) short bf16x8;
typedef __attribute__((ext_vector_type(8))) unsigned short ushort8;
typedef __attribute__((ext_vector_type(4))) float f32x4;
typedef __attribute__((ext_vector_type(4))) unsigned int uint4v;

#define SCALEf 2.0f
#define EPSf 1e-5f
#define SP3 262144            // 64^3

// ws layout:
//   floats  [0, 8448)      : accum[zo=66][n=16][co=8]
//   floats  [8448, 8464)   : Aaff[8], Baff[8]
//   bytes   [34816, 41984) : wfrag bf16 [7 groups][64 lanes][8]
//   bytes   [65536, ...)   : xt bf16 [16][64^3][8ci]   (67.1 MB)
#define WS_AFF 8448
#define WS_WF_BYTE 34816
#define WS_XT_BYTE 65536

__device__ __forceinline__ unsigned short bfr(float f) {   // f32 -> bf16 RNE
    unsigned u = __float_as_uint(f);
    return (unsigned short)((u + 0x7FFFu + ((u >> 16) & 1u)) >> 16);
}

// ---- pass 1: x (fp32 NCDHW) -> xt (bf16, channels-last) ----
__global__ __launch_bounds__(256) void xt_kernel(const float* __restrict__ x,
                                                 unsigned short* __restrict__ xt) {
    int gid = blockIdx.x * 256 + threadIdx.x;     // 2,097,152 threads, 2 pts each
    int q = gid * 2;
    int n = q >> 18;
    int rem = q & (SP3 - 1);
    const float* xp = x + (((size_t)n * 8) << 18) + rem;
    ushort8 v0, v1;
#pragma unroll
    for (int ci = 0; ci < 8; ci++) {
        float2 v = *(const float2*)(xp + ((size_t)ci << 18));
        v0[ci] = bfr(v.x);
        v1[ci] = bfr(v.y);
    }
    *(ushort8*)(xt + (size_t)q * 8) = v0;
    *(ushort8*)(xt + (size_t)q * 8 + 8) = v1;
}

// ---- pass 2: zero accum, fold affine, build weight fragments ----
__global__ void prep_kernel(const float* __restrict__ w, const float* __restrict__ bias,
                            const float* __restrict__ mean, const float* __restrict__ var,
                            const float* __restrict__ gamma, const float* __restrict__ beta,
                            float* __restrict__ wsf, unsigned short* __restrict__ wfrag) {
    int gid = blockIdx.x * 256 + threadIdx.x;
    if (gid < 8448) wsf[gid] = 0.0f;
    if (gid >= 8448 && gid < 8456) {
        int co = gid - 8448;
        float inv = rsqrtf(var[co] + EPSf);
        wsf[WS_AFF + co] = SCALEf * inv * gamma[co];
        wsf[WS_AFF + 8 + co] = (bias[co] * SCALEf - mean[co]) * inv * gamma[co] + beta[co];
    }
    int i = gid - 8704;
    if (i >= 0 && i < 3584) {                 // wfrag[g][lane][j]
        int j = i & 7;                        // ci
        int l = (i >> 3) & 63;                // lane
        int g = i >> 9;                       // K-group
        int col = l & 15, chunk = l >> 4;
        int tap = g * 4 + chunk;
        float v = 0.0f;
        if (col < 8 && tap < 27) {            // zeros for co>=8 and pad tap
            int tz = tap / 9, ty = (tap / 3) % 3, tx = tap % 3;
            v = w[(col * 8 + j) * 27 + (2 - tz) * 9 + (2 - ty) * 3 + (2 - tx)];
        }
        wfrag[i] = bfr(v);
    }
}

// ---- pass 3: implicit-GEMM conv + affine + relu + partial sums ----
__global__ __launch_bounds__(256) void conv_kernel(const unsigned short* __restrict__ xt,
                                                   const float* __restrict__ wsf,
                                                   const unsigned short* __restrict__ wfrag,
                                                   float* __restrict__ accum) {
    __shared__ unsigned short slab[20 * 68 * 8];   // [row<=19][x 68][ci 8], 21760 B
    __shared__ float red[4][8];

    const int tid = threadIdx.x;
    const int lane = tid & 63, wave = tid >> 6;
    const int col = lane & 15, chunk = lane >> 4;
    const int ybase = blockIdx.x * 4;
    const int zo = blockIdx.y, n = blockIdx.z;
    const int npts = min(264, (66 - ybase) * 66);

    bf16x8 bfrag[7];
#pragma unroll
    for (int g = 0; g < 7; g++)
        bfrag[g] = *(const bf16x8*)(wfrag + (g * 64 + lane) * 8);

    float Aaff = wsf[WS_AFF + col];       // col>=8 reads harmless bytes; masked below
    float Baff = wsf[WS_AFF + 8 + col];

    int cg[7];                            // per-lane byte offset of (tap) in slab
#pragma unroll
    for (int g = 0; g < 7; g++) {
        int tap = g * 4 + chunk;
        if (tap > 26) tap = 26;           // pad tap: any finite data (B-frag is 0)
        int tz = tap / 9, ty = (tap / 3) % 3, tx = tap % 3;
        cg[g] = ((tz * 6 + ty) * 68 + tx) * 16;
    }

    // stage [3 z][6 y][68 x][8 ci] bf16 slab with zero halo
    {
        const size_t xtn = ((size_t)n) << 18;
        for (int u = tid; u < 18 * 68; u += 256) {
            int x16 = u % 68;
            int row = u / 68;
            int tz = row / 6, yr = row - tz * 6;
            int zi = zo - 2 + tz, yi = ybase - 2 + yr, xi = x16 - 2;
            uint4v v = {0u, 0u, 0u, 0u};
            if ((unsigned)zi < 64u && (unsigned)yi < 64u && (unsigned)xi < 64u)
                v = *(const uint4v*)(xt + ((xtn + (size_t)((zi * 64 + yi) * 64 + xi)) << 3));
            *(uint4v*)(slab + (size_t)u * 8) = v;
        }
    }
    __syncthreads();

    const char* slabc = (const char*)slab;
    float sum = 0.0f;
#pragma unroll 1
    for (int tt = 0; tt < 5; tt++) {       // wave handles tiles t = wave, wave+4, ...
        int t = wave + tt * 4;
        if (t >= 17 || t * 16 >= npts) break;
        int p = t * 16 + col;              // A-row = lane&15 -> output point id
        int wy = p / 66;
        int xo = p - wy * 66;
        int abase = (wy * 68 + xo) * 16;
        f32x4 acc = {0.f, 0.f, 0.f, 0.f};
#pragma unroll
        for (int g = 0; g < 7; g++) {
            bf16x8 a = *(const bf16x8*)(slabc + abase + cg[g]);
            acc = __builtin_amdgcn_mfma_f32_16x16x32_bf16(a, bfrag[g], acc, 0, 0, 0);
        }
        int prow = t * 16 + chunk * 4;     // C/D: col=lane&15, row=(lane>>4)*4+j
#pragma unroll
        for (int j = 0; j < 4; j++) {
            float v = fmaxf(fmaf(Aaff, acc[j], Baff), 0.0f);
            bool ok = (col < 8) && (prow + j < npts);
            sum += ok ? v : 0.0f;
        }
    }

    // lanes sharing a col: l, l^16, l^32, l^48
    sum += __shfl_xor(sum, 16, 64);
    sum += __shfl_xor(sum, 32, 64);
    if (lane < 8) red[wave][lane] = sum;
    __syncthreads();
    if (tid < 8) {
        float s = red[0][tid] + red[1][tid] + red[2][tid] + red[3][tid];
        atomicAdd(&accum[zo * 128 + n * 8 + tid], s);
    }
}

__global__ void finalize_kernel(const float* __restrict__ accum, float* __restrict__ out) {
    int t = threadIdx.x;                   // 128 = n*8+co
    float s = 0.0f;
    for (int zo = 0; zo < 66; zo++) s += accum[zo * 128 + t];
    out[t] = s * (1.0f / (66.0f * 66.0f * 66.0f));
}

extern "C" void kernel_launch(void* const* d_in, const int* in_sizes, int n_in,
                              void* d_out, int out_size, void* d_ws, size_t ws_size,
                              hipStream_t stream) {
    const float* x      = (const float*)d_in[0];
    const float* weight = (const float*)d_in[1];
    const float* bias   = (const float*)d_in[2];
    const float* rmean  = (const float*)d_in[3];
    const float* rvar   = (const float*)d_in[4];
    const float* gamma  = (const float*)d_in[5];
    const float* beta   = (const float*)d_in[6];

    float* wsf = (float*)d_ws;
    unsigned short* wfrag = (unsigned short*)((char*)d_ws + WS_WF_BYTE);
    unsigned short* xt = (unsigned short*)((char*)d_ws + WS_XT_BYTE);
    float* out = (float*)d_out;

    xt_kernel<<<8192, 256, 0, stream>>>(x, xt);
    prep_kernel<<<48, 256, 0, stream>>>(weight, bias, rmean, rvar, gamma, beta, wsf, wfrag);
    conv_kernel<<<dim3(17, 66, 16), 256, 0, stream>>>(xt, wsf, wfrag, wsf);
    finalize_kernel<<<1, 128, 0, stream>>>(wsf, out);
}

// Round 3
// 253.899 us; speedup vs baseline: 1.7667x; 1.0545x over previous
//
#include <hip/hip_runtime.h>

typedef __attribute__((ext_vector_type(8))) short bf16x8;
typedef __attribute__((ext_vector_type(8))) unsigned short ushort8;
typedef __attribute__((ext_vector_type(4))) float f32x4;
typedef __attribute__((ext_vector_type(4))) unsigned int uint4v;

#define SCALEf 2.0f
#define EPSf 1e-5f

// ws layout:
//   floats [0, 4224)       : accum[zb=33][n=16][co=8]
//   floats [8448, 8464)    : Aaff[8], Baff[8]
//   bytes  [34816, 44032)  : wfrag bf16 [9 groups][64 lanes][8]
//   bytes  [65536, ...)    : xt bf16 [16][64^3][8ci]  (64 MiB)
#define WS_AFF 8448
#define WS_WF_BYTE 34816
#define WS_XT_BYTE 65536

__device__ __forceinline__ unsigned short bfr(float f) {   // f32 -> bf16 RNE
    unsigned u = __float_as_uint(f);
    return (unsigned short)((u + 0x7FFFu + ((u >> 16) & 1u)) >> 16);
}

// ---- pass 1: x (fp32 NCDHW) -> xt (bf16, channels-last) ----
__global__ __launch_bounds__(256) void xt_kernel(const float* __restrict__ x,
                                                 unsigned short* __restrict__ xt) {
    int gid = blockIdx.x * 256 + threadIdx.x;     // 1,048,576 threads, 4 pts each
    int q = gid * 4;
    int n = q >> 18;
    int rem = q & 262143;
    const float* xp = x + ((size_t)n << 21) + rem;
    float4 L[8];
#pragma unroll
    for (int ci = 0; ci < 8; ci++) L[ci] = *(const float4*)(xp + ((size_t)ci << 18));
    ushort8 o0, o1, o2, o3;
#pragma unroll
    for (int ci = 0; ci < 8; ci++) {
        o0[ci] = bfr(L[ci].x); o1[ci] = bfr(L[ci].y);
        o2[ci] = bfr(L[ci].z); o3[ci] = bfr(L[ci].w);
    }
    unsigned short* dst = xt + (size_t)q * 8;
    *(ushort8*)(dst)      = o0;
    *(ushort8*)(dst + 8)  = o1;
    *(ushort8*)(dst + 16) = o2;
    *(ushort8*)(dst + 24) = o3;
}

// ---- pass 2: zero accum, fold affine, build weight fragments (y-pair packed) ----
__global__ void prep_kernel(const float* __restrict__ w, const float* __restrict__ bias,
                            const float* __restrict__ mean, const float* __restrict__ var,
                            const float* __restrict__ gamma, const float* __restrict__ beta,
                            float* __restrict__ wsf, unsigned short* __restrict__ wfrag) {
    int gid = blockIdx.x * 256 + threadIdx.x;
    if (gid < 8448) wsf[gid] = 0.0f;
    if (gid >= 8448 && gid < 8456) {
        int co = gid - 8448;
        float inv = rsqrtf(var[co] + EPSf);
        wsf[WS_AFF + co] = SCALEf * inv * gamma[co];
        wsf[WS_AFF + 8 + co] = (bias[co] * SCALEf - mean[co]) * inv * gamma[co] + beta[co];
    }
    int i = gid - 8704;
    if (i >= 0 && i < 4608) {                 // wfrag[g][lane][j]
        int j = i & 7;                        // ci
        int l = (i >> 3) & 63;                // lane
        int g = i >> 9;                       // K-group 0..8
        int col = l & 15, chunk = l >> 4;
        int co = col & 7, ysub = col >> 3;    // N = 8 c_out x 2 y-sub
        int tap = g * 4 + chunk;              // 0..35 : (tz, tyext 0..3, tx)
        int tz = tap / 12, tyext = (tap / 3) & 3, tx = tap % 3;
        int ey = tyext - ysub;
        float v = 0.0f;
        if (ey >= 0 && ey <= 2)
            v = w[(co * 8 + j) * 27 + (2 - tz) * 9 + (2 - ey) * 3 + (2 - tx)];
        wfrag[i] = bfr(v);
    }
}

// ---- pass 3: implicit-GEMM conv (y-pair, 2 zo per block) + affine + relu + sums ----
__global__ __launch_bounds__(256) void conv_kernel(const unsigned short* __restrict__ xt,
                                                   const float* __restrict__ wsf,
                                                   const unsigned short* __restrict__ wfrag,
                                                   float* __restrict__ accum) {
    __shared__ unsigned short slab[1632 * 8];   // [z 4][y 6][x 68][ci 8] = 26112 B
    __shared__ float red[4][8];

    const int tid = threadIdx.x;
    const int lane = tid & 63, wave = tid >> 6;
    const int col = lane & 15, chunk = lane >> 4;
    const int ybase = blockIdx.x * 4;           // 0,4,...,64
    const int zo0 = blockIdx.y * 2;             // 0,2,...,64
    const int n = blockIdx.z;
    const int npairs = min(2, (66 - ybase) >> 1);
    const int nvalid = npairs * 66;             // valid base points
    const int ntile = (nvalid + 15) >> 4;       // 9 or 5

    bf16x8 bfrag[9];
#pragma unroll
    for (int g = 0; g < 9; g++)
        bfrag[g] = *(const bf16x8*)(wfrag + (g * 64 + lane) * 8);

    const float Aaff = wsf[WS_AFF + (col & 7)];
    const float Baff = wsf[WS_AFF + 8 + (col & 7)];

    int cg[9];                                  // per-lane tap byte offset in slab
#pragma unroll
    for (int g = 0; g < 9; g++) {
        int tap = g * 4 + chunk;
        int tz = tap / 12, tyext = (tap / 3) & 3, tx = tap % 3;
        cg[g] = ((tz * 6 + tyext) * 68 + tx) * 16;
    }

    // stage [4 z][6 y][68 x][8 ci] with zero halo
    {
        const unsigned short* xtn = xt + ((size_t)n << 21);
        for (int u = tid; u < 1632; u += 256) {
            int z = u / 408;                    // 408 = 6*68
            int rem = u - z * 408;
            int y = rem / 68;
            int xv = rem - y * 68;
            int zi = zo0 - 2 + z, yi = ybase - 2 + y, xi = xv - 2;
            uint4v v = {0u, 0u, 0u, 0u};
            if ((unsigned)zi < 64u && (unsigned)yi < 64u && (unsigned)xi < 64u)
                v = *(const uint4v*)(xtn + ((size_t)((zi * 64 + yi) * 64 + xi) << 3));
            *(uint4v*)(slab + (size_t)u * 8) = v;
        }
    }
    __syncthreads();

    const char* slabc = (const char*)slab;
    float sum = 0.0f;
    const int nflat = 2 * ntile;                // zs in {0,1}
    for (int i = wave; i < nflat; i += 4) {
        int zs = (i >= ntile) ? 1 : 0;
        int t = i - zs * ntile;
        int p = t * 16 + col;                   // A-row -> base point (pair-linear)
        if (p >= nvalid) p = 0;                 // clamp: keeps LDS reads in-bounds
        int pr = p / 66;
        int xo = p - pr * 66;
        int abase = ((zs * 6 + pr * 2) * 68 + xo) * 16;
        f32x4 acc = {0.f, 0.f, 0.f, 0.f};
#pragma unroll
        for (int g = 0; g < 9; g++) {
            bf16x8 a = *(const bf16x8*)(slabc + abase + cg[g]);
            acc = __builtin_amdgcn_mfma_f32_16x16x32_bf16(a, bfrag[g], acc, 0, 0, 0);
        }
        int m0 = t * 16 + chunk * 4;            // C/D rows for this lane
#pragma unroll
        for (int j = 0; j < 4; j++) {
            float v = fmaxf(fmaf(Aaff, acc[j], Baff), 0.0f);
            sum += (m0 + j < nvalid) ? v : 0.0f;
        }
    }

    // lanes sharing a co: xor over bits 3,4,5
    sum += __shfl_xor(sum, 8, 64);
    sum += __shfl_xor(sum, 16, 64);
    sum += __shfl_xor(sum, 32, 64);
    if (lane < 8) red[wave][lane] = sum;
    __syncthreads();
    if (tid < 8) {
        float s = red[0][tid] + red[1][tid] + red[2][tid] + red[3][tid];
        atomicAdd(&accum[blockIdx.y * 128 + n * 8 + tid], s);
    }
}

__global__ void finalize_kernel(const float* __restrict__ accum, float* __restrict__ out) {
    int t = threadIdx.x;                        // 128 = n*8+co
    float s = 0.0f;
    for (int zb = 0; zb < 33; zb++) s += accum[zb * 128 + t];
    out[t] = s * (1.0f / (66.0f * 66.0f * 66.0f));
}

extern "C" void kernel_launch(void* const* d_in, const int* in_sizes, int n_in,
                              void* d_out, int out_size, void* d_ws, size_t ws_size,
                              hipStream_t stream) {
    const float* x      = (const float*)d_in[0];
    const float* weight = (const float*)d_in[1];
    const float* bias   = (const float*)d_in[2];
    const float* rmean  = (const float*)d_in[3];
    const float* rvar   = (const float*)d_in[4];
    const float* gamma  = (const float*)d_in[5];
    const float* beta   = (const float*)d_in[6];

    float* wsf = (float*)d_ws;
    unsigned short* wfrag = (unsigned short*)((char*)d_ws + WS_WF_BYTE);
    unsigned short* xt = (unsigned short*)((char*)d_ws + WS_XT_BYTE);
    float* out = (float*)d_out;

    xt_kernel<<<4096, 256, 0, stream>>>(x, xt);
    prep_kernel<<<52, 256, 0, stream>>>(weight, bias, rmean, rvar, gamma, beta, wsf, wfrag);
    conv_kernel<<<dim3(17, 33, 16), 256, 0, stream>>>(xt, wsf, wfrag, wsf);
    finalize_kernel<<<1, 128, 0, stream>>>(wsf, out);
}

// Round 4
// 217.543 us; speedup vs baseline: 2.0620x; 1.1671x over previous
//
#include <hip/hip_runtime.h>

typedef __attribute__((ext_vector_type(8))) short bf16x8;
typedef __attribute__((ext_vector_type(8))) unsigned short ushort8;
typedef __attribute__((ext_vector_type(4))) float f32x4;

#define SCALEf 2.0f
#define EPSf 1e-5f

// ws layout:
//   floats [0, 2176)    : accum[zb=17][n=16][co=8]
//   floats [2176, 2192) : Aaff[8], Baff[8]
//   bytes  [32768, +24576) : wfrag bf16 [12 g][2 zsub][64 lane][8 ci]
#define WS_AFF 2176
#define WS_WF_BYTE 32768

__device__ __forceinline__ unsigned short bfr(float f) {   // f32 -> bf16 RNE
    unsigned u = __float_as_uint(f);
    return (unsigned short)((u + 0x7FFFu + ((u >> 16) & 1u)) >> 16);
}

// ---- pass 1: zero accum, fold affine, build weight fragments ----
// taps extended: tzext 0..3, tyext 0..3, tx 0..2 (48 taps, 12 groups of 4)
__global__ void prep_kernel(const float* __restrict__ w, const float* __restrict__ bias,
                            const float* __restrict__ mean, const float* __restrict__ var,
                            const float* __restrict__ gamma, const float* __restrict__ beta,
                            float* __restrict__ wsf, unsigned short* __restrict__ wfrag) {
    int gid = blockIdx.x * 256 + threadIdx.x;
    if (gid < 2176) wsf[gid] = 0.0f;
    if (gid >= 2176 && gid < 2184) {
        int co = gid - 2176;
        float inv = rsqrtf(var[co] + EPSf);
        wsf[WS_AFF + co] = SCALEf * inv * gamma[co];
        wsf[WS_AFF + 8 + co] = (bias[co] * SCALEf - mean[co]) * inv * gamma[co] + beta[co];
    }
    int i = gid - 4096;
    if (i >= 0 && i < 12288) {                // wfrag[g][zsub][lane][ci]
        int j = i & 7;                        // ci
        int l = (i >> 3) & 63;                // lane
        int gz = i >> 9;                      // 0..23
        int g = gz >> 1, zsub = gz & 1;
        int col = l & 15, chunk = l >> 4;
        int co = col & 7, ysub = col >> 3;
        int tap = g * 4 + chunk;              // 0..47
        int tz = tap / 12, ty = (tap % 12) / 3, tx = tap % 3;
        int ez = tz - zsub, ey = ty - ysub;
        float v = 0.0f;
        if (ez >= 0 && ez <= 2 && ey >= 0 && ey <= 2)
            v = w[(co * 8 + j) * 27 + (2 - ez) * 9 + (2 - ey) * 3 + (2 - tx)];
        wfrag[i] = bfr(v);
    }
}

// ---- pass 2: fused convert+stage + implicit-GEMM conv + affine + relu + sums ----
// block: 4 zo x 4 yo x 66 x ; slab [z 6][y 6][x 68][ci 8] bf16
__global__ __launch_bounds__(256) void conv_kernel(const float* __restrict__ x,
                                                   const float* __restrict__ wsf,
                                                   const unsigned short* __restrict__ wfrag,
                                                   float* __restrict__ accum) {
    __shared__ unsigned short slab[2448 * 8];   // 39168 B
    __shared__ float red[4][8];

    const int tid = threadIdx.x;
    const int lane = tid & 63, wave = tid >> 6;
    const int col = lane & 15, chunk = lane >> 4;
    const int ybase = blockIdx.x * 4;           // 0,4,...,64
    const int zo0 = blockIdx.y * 4;             // 0,4,...,64
    const int n = blockIdx.z;

    // B fragments: 12 groups x 2 zsub
    bf16x8 b0[12], b1[12];
#pragma unroll
    for (int g = 0; g < 12; g++) {
        b0[g] = *(const bf16x8*)(wfrag + ((g * 2 + 0) * 64 + lane) * 8);
        b1[g] = *(const bf16x8*)(wfrag + ((g * 2 + 1) * 64 + lane) * 8);
    }

    const float Aaff = wsf[WS_AFF + (col & 7)];
    const float Baff = wsf[WS_AFF + 8 + (col & 7)];

    int cg[12];                                 // per-lane tap byte offset in slab
#pragma unroll
    for (int g = 0; g < 12; g++) {
        int tap = g * 4 + chunk;
        int tz = tap / 12, ty = (tap % 12) / 3, tx = tap % 3;
        cg[g] = ((tz * 6 + ty) * 68 + tx) * 16;
    }

    // ---- stage: read x fp32 directly, convert to bf16 channels-last ----
    {
        const float* xn = x + ((size_t)n << 21);
        for (int u = tid; u < 576; u += 256) {  // 36 rows x 16 x-quads
            int k = u & 15, row = u >> 4;       // row = z*6+y
            int z = row / 6, yy = row - z * 6;
            int zi = zo0 - 2 + z, yi = ybase - 2 + yy;
            unsigned short* dst = slab + ((size_t)row * 68 + 2 + k * 4) * 8;
            if ((unsigned)zi < 64u && (unsigned)yi < 64u) {
                const float* xp = xn + ((zi * 64 + yi) * 64 + k * 4);
                ushort8 o0, o1, o2, o3;
#pragma unroll
                for (int ci = 0; ci < 8; ci++) {
                    float4 v = *(const float4*)(xp + ((size_t)ci << 18));
                    o0[ci] = bfr(v.x); o1[ci] = bfr(v.y);
                    o2[ci] = bfr(v.z); o3[ci] = bfr(v.w);
                }
                *(ushort8*)(dst)      = o0;
                *(ushort8*)(dst + 8)  = o1;
                *(ushort8*)(dst + 16) = o2;
                *(ushort8*)(dst + 24) = o3;
            } else {
                ushort8 zz = {0, 0, 0, 0, 0, 0, 0, 0};
                *(ushort8*)(dst)      = zz;
                *(ushort8*)(dst + 8)  = zz;
                *(ushort8*)(dst + 16) = zz;
                *(ushort8*)(dst + 24) = zz;
            }
        }
        // x-halo pad zeros: 36 rows x {x=0,1} and {x=66,67}
        if (tid < 72) {
            int row = tid >> 1, side = tid & 1;
            unsigned short* dst = slab + ((size_t)row * 68 + side * 66) * 8;
            ushort8 zz = {0, 0, 0, 0, 0, 0, 0, 0};
            *(ushort8*)(dst)     = zz;
            *(ushort8*)(dst + 8) = zz;
        }
    }
    __syncthreads();

    // ---- main: M=264 base pts (zt,yt,x) in 17 tiles; 12 K-groups; 2 MFMA/A-read ----
    const char* slabc = (const char*)slab;
    float sum = 0.0f;
    for (int t = wave; t < 17; t += 4) {
        int p = t * 16 + col;                   // A-row -> base point
        if (p >= 264) p = 0;                    // clamp for in-bounds reads
        int zt = (p >= 132) ? 1 : 0;
        int rem = p - zt * 132;
        int yt = (rem >= 66) ? 1 : 0;
        int xo = rem - yt * 66;
        int abase = ((zt * 2 * 6 + yt * 2) * 68 + xo) * 16;
        f32x4 acc0 = {0.f, 0.f, 0.f, 0.f};
        f32x4 acc1 = {0.f, 0.f, 0.f, 0.f};
#pragma unroll
        for (int g = 0; g < 12; g++) {
            bf16x8 a = *(const bf16x8*)(slabc + abase + cg[g]);
            acc0 = __builtin_amdgcn_mfma_f32_16x16x32_bf16(a, b0[g], acc0, 0, 0, 0);
            acc1 = __builtin_amdgcn_mfma_f32_16x16x32_bf16(a, b1[g], acc1, 0, 0, 0);
        }
        // epilogue: C/D row m -> base point; col -> (co, ysub); accN -> zsub=N
#pragma unroll
        for (int j = 0; j < 4; j++) {
            int m = t * 16 + chunk * 4 + j;
            int mzt = (m >= 132) ? 1 : 0;
            int mrem = m - mzt * 132;
            int myt = (mrem >= 66) ? 1 : 0;
            bool mv = (m < 264);
            int yo = ybase + myt * 2 + (col >> 3);
            int zoA = zo0 + mzt * 2;
            bool vy = mv && (yo < 66);
            float v0 = fmaxf(fmaf(Aaff, acc0[j], Baff), 0.0f);
            float v1 = fmaxf(fmaf(Aaff, acc1[j], Baff), 0.0f);
            sum += (vy && (zoA < 66)) ? v0 : 0.0f;
            sum += (vy && (zoA + 1 < 66)) ? v1 : 0.0f;
        }
    }

    // reduce lanes sharing co (= lane&7): xor bits 3,4,5
    sum += __shfl_xor(sum, 8, 64);
    sum += __shfl_xor(sum, 16, 64);
    sum += __shfl_xor(sum, 32, 64);
    if (lane < 8) red[wave][lane] = sum;
    __syncthreads();
    if (tid < 8) {
        float s = red[0][tid] + red[1][tid] + red[2][tid] + red[3][tid];
        atomicAdd(&accum[blockIdx.y * 128 + n * 8 + tid], s);
    }
}

__global__ void finalize_kernel(const float* __restrict__ accum, float* __restrict__ out) {
    int t = threadIdx.x;                        // 128 = n*8+co
    float s = 0.0f;
    for (int zb = 0; zb < 17; zb++) s += accum[zb * 128 + t];
    out[t] = s * (1.0f / (66.0f * 66.0f * 66.0f));
}

extern "C" void kernel_launch(void* const* d_in, const int* in_sizes, int n_in,
                              void* d_out, int out_size, void* d_ws, size_t ws_size,
                              hipStream_t stream) {
    const float* x      = (const float*)d_in[0];
    const float* weight = (const float*)d_in[1];
    const float* bias   = (const float*)d_in[2];
    const float* rmean  = (const float*)d_in[3];
    const float* rvar   = (const float*)d_in[4];
    const float* gamma  = (const float*)d_in[5];
    const float* beta   = (const float*)d_in[6];

    float* wsf = (float*)d_ws;
    unsigned short* wfrag = (unsigned short*)((char*)d_ws + WS_WF_BYTE);
    float* out = (float*)d_out;

    prep_kernel<<<64, 256, 0, stream>>>(weight, bias, rmean, rvar, gamma, beta, wsf, wfrag);
    conv_kernel<<<dim3(17, 17, 16), 256, 0, stream>>>(x, wsf, wfrag, wsf);
    finalize_kernel<<<1, 128, 0, stream>>>(wsf, out);
}